// Round 2
// 302.977 us; speedup vs baseline: 1.0178x; 1.0178x over previous
//
#include <hip/hip_runtime.h>

// Adaptive db4 wavelet transform, 5-level cascade, per-feature level select.
// B=32, S=4096, F=64, (b,s,f) f-contiguous. 16B vector lanes across f.
//
// 5 regular launches (cooperative launch fails under harness graph capture):
//   K1..K4 (full-region grids, 8192 blocks): head waves compute lo_j (ws) +
//     det_j head; tail waves nt-store zeros. Each det region written once,
//     contiguously, by one kernel (fill-like tail stream).
//   K5 (region-major, 32768 blocks): region = tid>>21 selects ONE output
//     stream per wave: approx | low_freq | det5 | high_freq. Shared work
//     (level-5 conv, lo gathers) recomputed per region (n<128, LLC-warm).
//
// Output concat: approx[BSF] | det1..det5[5*BSF] | high_freq[BSF] | low_freq[BSF]

#define NB 32
#define NS 4096
#define NF 64
#define BSF (NB * NS * NF)
#define NF4 (NF / 4)

typedef float f4v __attribute__((ext_vector_type(4)));

__constant__ float c_h0[8] = {
     0.23037781330885523f,  0.7148465705525415f,   0.6308807679295904f,
    -0.02798376941698385f, -0.18703481171888114f,  0.030841381835986965f,
     0.032883011666982945f, -0.010597401784997278f};
__constant__ float c_h1[8] = {
    -0.010597401784997278f, -0.032883011666982945f, 0.030841381835986965f,
     0.18703481171888114f,  -0.02798376941698385f,  -0.6308807679295904f,
     0.7148465705525415f,   -0.23037781330885523f};

__device__ __forceinline__ int get_level(const float* __restrict__ scores, int f) {
    int lv = 2 + (int)rintf(scores[f] * 3.0f);   // round-half-even, matches jnp
    return min(5, max(2, lv));
}

// Level kernel over the FULL det_J region: n < LEN -> compute lo_J (ws) and
// det_J head; n >= LEN -> nt-store zero tail. Wave = 4 consecutive n rows, so
// the head/tail branch is wave-uniform.
template <int J, int TIN, int LOG2LEN>
__global__ __launch_bounds__(256) void wl_lvl(
    const f4v* __restrict__ in, f4v* __restrict__ lo_out,
    f4v* __restrict__ det, const float* __restrict__ scores)
{
    constexpr int LEN = 1 << LOG2LEN;
    int t = blockIdx.x * 256 + threadIdx.x;        // grid = NB*NS*NF4 threads
    int f4 = t & (NF4 - 1);
    int r = t >> 4;
    int n = r & (NS - 1);
    int b = r >> 12;

    f4v* dp = det + (size_t)(b * NS + n) * NF4 + f4;
    const f4v z = {0.f, 0.f, 0.f, 0.f};
    if (n >= LEN) {                                // zero tail: fill-like stream
        __builtin_nontemporal_store(z, dp);
        return;
    }

    const f4v* row = in + (size_t)b * TIN * NF4 + f4;
    int base = 2 * n - 3;
    f4v lo = z, hi = z;
#pragma unroll
    for (int i = 0; i < 8; ++i) {
        int m = base + i;
        if ((unsigned)m < (unsigned)TIN) {
            f4v v = row[(size_t)m * NF4];
            lo += c_h0[i] * v;
            hi += c_h1[i] * v;
        }
    }
    if (J >= 3) {                                  // det_J kept iff lv[f] >= J
        int f0 = f4 * 4;
#pragma unroll
        for (int c = 0; c < 4; ++c)
            if (get_level(scores, f0 + c) < J) hi[c] = 0.f;
    }
    lo_out[(size_t)(b * LEN + n) * NF4 + f4] = lo; // regular store: re-read next level
    dp[0] = hi;                                    // regular store: re-read by K5 high
    (void)dp;
}

// Final kernel, region-major: region = tid >> 21 (BSF/4 = 2^21 tasks/region).
//   r=0: approx   r=1: low_freq   r=2: det5   r=3: high_freq
// Each wave writes exactly one contiguous nt-store stream.
__global__ __launch_bounds__(256) void wl_final(
    const float* __restrict__ lo2s, const float* __restrict__ lo3s,
    const float* __restrict__ lo4s, f4v* __restrict__ out4,
    const float* __restrict__ scores)
{
    int t = blockIdx.x * 256 + threadIdx.x;        // grid = 4 * BSF/4 threads
    int reg = t >> 21;
    int idx = t & ((1 << 21) - 1);
    int f4 = idx & (NF4 - 1);
    int r = idx >> 4;
    int n = r & (NS - 1);
    int b = r >> 12;
    int f0 = f4 * 4;

    int lv[4];
#pragma unroll
    for (int c = 0; c < 4; ++c) lv[c] = get_level(scores, f0 + c);

    const f4v z = {0.f, 0.f, 0.f, 0.f};
    const f4v* lo4row = (const f4v*)lo4s + (size_t)b * 256 * NF4 + f4;

    f4v* det1 = out4 + (size_t)1 * (BSF / 4);
    f4v* det2 = out4 + (size_t)2 * (BSF / 4);
    f4v* det3 = out4 + (size_t)3 * (BSF / 4);
    f4v* det4 = out4 + (size_t)4 * (BSF / 4);

    if (reg <= 1) {
        // approx / low_freq: component c = lowpass after lv[c] levels, zero tail
        f4v l5 = z;
        if (n < 128 && (lv[0] == 5 || lv[1] == 5 || lv[2] == 5 || lv[3] == 5)) {
            int base = 2 * n - 3;
#pragma unroll
            for (int i = 0; i < 8; ++i) {
                int m = base + i;
                if ((unsigned)m < 256u) l5 += c_h0[i] * lo4row[(size_t)m * NF4];
            }
        }
        f4v av = z;
#pragma unroll
        for (int c = 0; c < 4; ++c) {
            int L = lv[c];
            int len = 2048 >> (L - 1);             // 1024/512/256/128 for L=2..5
            float vv = 0.f;
            if (n < len) {
                if (L == 5)      vv = l5[c];
                else if (L == 4) vv = lo4s[(size_t)(b * 256 + n) * NF + f0 + c];
                else if (L == 3) vv = lo3s[(size_t)(b * 512 + n) * NF + f0 + c];
                else             vv = lo2s[(size_t)(b * 1024 + n) * NF + f0 + c];
            }
            av[c] = vv;
        }
        f4v* dst = (reg == 0) ? (out4 + idx)                          // approx
                              : (out4 + (size_t)7 * (BSF / 4) + idx); // low_freq
        __builtin_nontemporal_store(av, dst);
        return;
    }

    // d5 needed by both det5 and high_freq regions
    f4v d5 = z;
    if (n < 128) {
        int base = 2 * n - 3;
        f4v hi = z;
#pragma unroll
        for (int i = 0; i < 8; ++i) {
            int m = base + i;
            if ((unsigned)m < 256u) hi += c_h1[i] * lo4row[(size_t)m * NF4];
        }
#pragma unroll
        for (int c = 0; c < 4; ++c) d5[c] = (lv[c] >= 5) ? hi[c] : 0.f;
    }

    if (reg == 2) {                                // det5 (mostly a zero fill)
        __builtin_nontemporal_store(d5, out4 + (size_t)5 * (BSF / 4) + idx);
        return;
    }

    // high_freq = sum of masked details (heads LLC-warm from K1..K4)
    f4v acc = d5;
    if (n < 2048) {
        acc += det1[idx];
        if (n < 1024) acc += det2[idx];
        if (n < 512)  acc += det3[idx];
        if (n < 256)  acc += det4[idx];
    }
    __builtin_nontemporal_store(acc, out4 + (size_t)6 * (BSF / 4) + idx);
}

extern "C" void kernel_launch(void* const* d_in, const int* in_sizes, int n_in,
                              void* d_out, int out_size, void* d_ws, size_t ws_size,
                              hipStream_t stream)
{
    const f4v* x        = (const f4v*)d_in[0];
    const float* scores = (const float*)d_in[1];
    f4v* out4 = (f4v*)d_out;
    float* ws = (float*)d_ws;

    // lo pyramid in workspace: (2048+1024+512+256) * NB*NF floats = 30 MiB
    f4v* lo1 = (f4v*)ws;
    f4v* lo2 = lo1 + (size_t)NB * 2048 * NF4;
    f4v* lo3 = lo2 + (size_t)NB * 1024 * NF4;
    f4v* lo4 = lo3 + (size_t)NB * 512 * NF4;

    f4v* det1 = out4 + (size_t)1 * (BSF / 4);
    f4v* det2 = out4 + (size_t)2 * (BSF / 4);
    f4v* det3 = out4 + (size_t)3 * (BSF / 4);
    f4v* det4 = out4 + (size_t)4 * (BSF / 4);

    dim3 block(256);
    const int FULL = NB * NS * NF4 / 256;          // 8192 blocks per level kernel
    wl_lvl<1, 4096, 11><<<dim3(FULL), block, 0, stream>>>(x,   lo1, det1, scores);
    wl_lvl<2, 2048, 10><<<dim3(FULL), block, 0, stream>>>(lo1, lo2, det2, scores);
    wl_lvl<3, 1024,  9><<<dim3(FULL), block, 0, stream>>>(lo2, lo3, det3, scores);
    wl_lvl<4,  512,  8><<<dim3(FULL), block, 0, stream>>>(lo3, lo4, det4, scores);
    wl_final<<<dim3(4 * FULL), block, 0, stream>>>((const float*)lo2, (const float*)lo3,
                                                   (const float*)lo4, out4, scores);
}